// Round 3
// baseline (228.231 us; speedup 1.0000x reference)
//
#include <hip/hip_runtime.h>
#include <math.h>

// ---------------------------------------------------------------------------
// Single-launch, communication-free fused Refiner.
//
// R8: grid-wide sync (coop or software barrier) costs 30-55us on this chip
// (R6/R7 post-mortem: device-scope fences against poison-dirty L2 + spin).
// So fuse WITHOUT communication: every block is self-sufficient.
//   - Each block recomputes the B pre-reduction ONLY for its dependence cone
//     (~250 of 784 entries, ~1.5M FMA/block ~ 5us) directly into LDS sB.
//     Conv channel weights (768x9) are held in 108 regs/lane, so each
//     768-dot reads just 12 coalesced fv floats per lane.
//   - Each block folds the full up2-x weight table WTf[112][224] into LDS
//     from W_w (L2-resident), replacing the global gWTf round-trip.
//   - No workspace, no memset, no barrier, no fences. One regular launch.
//
// Carried from earlier rounds (verified R5 phase-B body):
//  - B[s][t][u][v] = sum_c conv_w[1+c][t] * f14[s][c][u][v]; feature term of
//    every stage is one bilinear sample of B (BN affine commutes with lerp).
//  - Final up2-x folded into weights WTf[xx][o]; per-y4-row dots D[i][o]
//    (K=112) then up2-y lerp of D rows at the end.
//  - Cone row windows per stage; stage 1 uses integer B lookup.
// ---------------------------------------------------------------------------

#define BN_EPS 1e-5f

__device__ __forceinline__ float clampf(float x, float lo, float hi) {
    return fminf(fmaxf(x, lo), hi);
}

__device__ __forceinline__ float sampleB(const float* __restrict__ Bt, float fy, float fx) {
    int y0 = (int)fy; float by = fy - (float)y0; int y1 = min(y0 + 1, 13);
    int x0 = (int)fx; float bx = fx - (float)x0; int x1 = min(x0 + 1, 13);
    return (1.f - by) * ((1.f - bx) * Bt[y0 * 14 + x0] + bx * Bt[y0 * 14 + x1])
         + by         * ((1.f - bx) * Bt[y1 * 14 + x0] + bx * Bt[y1 * 14 + x1]);
}

// Conv accumulator (pre-ReLU/BN) for one pixel at resolution H (up-sampled h).
__device__ __forceinline__ float stage_pixel(int i, int j, int H,
                                             const float* __restrict__ hsrc, int srcH,
                                             const float* __restrict__ sB,
                                             const float* __restrict__ cw, float bias) {
    float featScale = 14.0f / (float)H;
    float srcMax = (float)(srcH - 1);
    float acc = bias;

#pragma unroll
    for (int a = 0; a < 3; ++a) {
        int p = i + a - 1;
        if (p < 0 || p >= H) continue;          // SAME zero padding
        float fy = clampf(((float)p + 0.5f) * featScale - 0.5f, 0.f, 13.f);
        float hy = clampf(((float)p + 0.5f) * 0.5f - 0.5f, 0.f, srcMax);
        int hy0 = (int)hy; float fhy = hy - (float)hy0; int hy1 = min(hy0 + 1, srcH - 1);
#pragma unroll
        for (int bq = 0; bq < 3; ++bq) {
            int q = j + bq - 1;
            if (q < 0 || q >= H) continue;
            int t = a * 3 + bq;

            float fx = clampf(((float)q + 0.5f) * featScale - 0.5f, 0.f, 13.f);
            float bv = sampleB(sB + t * 196, fy, fx);

            float hx = clampf(((float)q + 0.5f) * 0.5f - 0.5f, 0.f, srcMax);
            int hx0 = (int)hx; float fhx = hx - (float)hx0; int hx1 = min(hx0 + 1, srcH - 1);
            float hval = (1.f - fhy) * ((1.f - fhx) * hsrc[hy0 * srcH + hx0] + fhx * hsrc[hy0 * srcH + hx1])
                       + fhy         * ((1.f - fhx) * hsrc[hy1 * srcH + hx0] + fhx * hsrc[hy1 * srcH + hx1]);
            acc += cw[t] * hval + bv;
        }
    }
    return acc;
}

// src rows needed to compute dst rows [dlo,dhi] of a stage at H=2*srcH.
__device__ __forceinline__ void srcRange(int dlo, int dhi, int srcH, int& slo, int& shi) {
    int H = 2 * srcH;
    int p0 = max(dlo - 1, 0), p1 = min(dhi + 1, H - 1);
    float h0 = fmaxf(((float)p0 + 0.5f) * 0.5f - 0.5f, 0.f);
    float h1 = fmaxf(((float)p1 + 0.5f) * 0.5f - 0.5f, 0.f);
    slo = (int)h0;
    shi = min((int)h1 + 1, srcH - 1);
}

// B-plane rows of a stage's sB needed for dst rows [dlo,dhi] at resolution H.
__device__ __forceinline__ void bRange(int dlo, int dhi, int H, int& lo, int& hi) {
    float sc = 14.f / (float)H;
    int p0 = max(dlo - 1, 0), p1 = min(dhi + 1, H - 1);
    float f0 = clampf(((float)p0 + 0.5f) * sc - 0.5f, 0.f, 13.f);
    float f1 = clampf(((float)p1 + 0.5f) * sc - 0.5f, 0.f, 13.f);
    lo = (int)f0;
    hi = min((int)f1 + 1, 13);
}

__global__ __launch_bounds__(1024, 1)
void refine_one(const float* __restrict__ x, const float* __restrict__ fv,
                const float* __restrict__ conv_w, const float* __restrict__ conv_b,
                const float* __restrict__ bng, const float* __restrict__ bnb,
                const float* __restrict__ bnm, const float* __restrict__ bnv,
                const float* __restrict__ W_w, const float* __restrict__ W_b,
                float* __restrict__ out) {
    __shared__ float sB[4 * 9 * 196];      //  28224 B
    __shared__ float y1s[196];             //    784 B
    __shared__ float y2s[784];             //   3136 B
    __shared__ float y3s[3136];            //  12544 B
    __shared__ float y4loc[3 * 112];       //   1344 B
    __shared__ float partial[12 * 224];    //  10752 B
    __shared__ float sWTf[112 * 224];      // 100352 B   -> total 157136 B

    int tid = threadIdx.x;
    int b = blockIdx.x;
    int wave = tid >> 6, lane = tid & 63;

    // ---- dependence cone of output rows 2b, 2b+1 (same windows as R5) ----
    int y4lo = max(b - 1, 0), y4hi = min(b + 1, 111);
    int r3lo, r3hi; srcRange(y4lo, y4hi, 56, r3lo, r3hi);
    int r2lo, r2hi; srcRange(r3lo, r3hi, 28, r2lo, r2hi);
    int r1lo, r1hi; srcRange(r2lo, r2hi, 14, r1lo, r1hi);

    int bl0 = max(r1lo - 1, 0), bh0 = min(r1hi + 1, 13);   // stage 1: integer coords
    int bl1, bh1; bRange(r2lo, r2hi, 28, bl1, bh1);
    int bl2, bh2; bRange(r3lo, r3hi, 56, bl2, bh2);
    int bl3, bh3; bRange(y4lo, y4hi, 112, bl3, bh3);

    int n0  = (bh0 - bl0 + 1) * 14;
    int n1p = (bh1 - bl1 + 1) * 14;
    int n2p = (bh2 - bl2 + 1) * 14;
    int n3p = (bh3 - bl3 + 1) * 14;
    int off1 = n0, off2 = n0 + n1p, off3 = n0 + n1p + n2p;
    int Ne = off3 + n3p;                 // <= ~252 cone B-entries

    // ---- conv channel weights for this lane's channels, in registers ----
    // lane handles channels c = lane + 64*i, i<12 (768 total per wave).
    float cwreg[12][9];
#pragma unroll
    for (int i = 0; i < 12; ++i) {
        const float* wp = conv_w + (size_t)(1 + lane + 64 * i) * 9;
#pragma unroll
        for (int t = 0; t < 9; ++t) cwreg[i][t] = wp[t];
    }

    // ---- Phase A1: cone-only B recompute into sB (no cross-block comm) ----
    // Entry e -> (plane s, uv). Each wave takes a contiguous chunk.
    {
        int chunk = (Ne + 15) >> 4;
        int e0 = wave * chunk, e1 = min(e0 + chunk, Ne);
        for (int e = e0; e < e1; ++e) {
            int s = (e >= off1) + (e >= off2) + (e >= off3);
            int base = (s == 0) ? 0   : (s == 1) ? off1 : (s == 2) ? off2 : off3;
            int bls  = (s == 0) ? bl0 : (s == 1) ? bl1  : (s == 2) ? bl2  : bl3;
            int uv = bls * 14 + (e - base);
            const float* fvrow = fv + ((size_t)(3 - s) * 197 + 1 + uv) * 768 + lane;
            float acc[9];
#pragma unroll
            for (int t = 0; t < 9; ++t) acc[t] = 0.f;
#pragma unroll
            for (int i = 0; i < 12; ++i) {
                float f = fvrow[64 * i];          // coalesced 256B per instr
#pragma unroll
                for (int t = 0; t < 9; ++t) acc[t] += cwreg[i][t] * f;
            }
#pragma unroll
            for (int t = 0; t < 9; ++t) {
#pragma unroll
                for (int off = 32; off > 0; off >>= 1)
                    acc[t] += __shfl_down(acc[t], off, 64);
            }
            if (lane == 0) {
                int db = s * 1764 + uv;
#pragma unroll
                for (int t = 0; t < 9; ++t) sB[db + t * 196] = acc[t];
            }
        }
    }

    float cw[9];
#pragma unroll
    for (int t = 0; t < 9; ++t) cw[t] = conv_w[t];
    float bias = conv_b[0];
    float scale = bng[0] * rsqrtf(bnv[0] + BN_EPS);
    float shift = bnb[0] - bnm[0] * scale;
    __syncthreads();   // sB ready

    // ---- Phase A2: WTf fold into LDS (tid<896) || stage 1 (tid>=896) ----
    if (tid < 896) {
        // thread (o, seg): o stable -> W_w row read is sequential per thread,
        // sWTf write coalesced over o. sWTf[xx][o] = sum_d coef*W_w[o][2xx+d].
        int o = tid % 224;
        int seg = tid / 224;                      // 0..3, 28 xx each
        for (int xx = seg * 28; xx < seg * 28 + 28; ++xx) {
            float acc = 0.f;
#pragma unroll
            for (int d = -1; d <= 2; ++d) {
                int w = 2 * xx + d;
                if (w < 0 || w > 223) continue;
                float hx = clampf(((float)w + 0.5f) * 0.5f - 0.5f, 0.f, 111.f);
                int xx0 = (int)hx; float fx = hx - (float)xx0; int xx1 = min(xx0 + 1, 111);
                float c = (xx0 == xx ? 1.f - fx : 0.f) + (xx1 == xx ? fx : 0.f);
                acc += c * W_w[o * 224 + w];
            }
            sWTf[xx * 224 + o] = acc;
        }
    } else {
        // Stage 1 (14x14, h = x, B sampled at integer coords -> direct lookup)
        int t2 = tid - 896;                       // cone rows *14 <= ~98 < 128
        int n = (r1hi - r1lo + 1) * 14;
        if (t2 < n) {
            int i = r1lo + t2 / 14, j = t2 % 14;
            float acc = bias;
#pragma unroll
            for (int a = 0; a < 3; ++a) {
                int p = i + a - 1;
                if (p < 0 || p >= 14) continue;
#pragma unroll
                for (int bq = 0; bq < 3; ++bq) {
                    int q = j + bq - 1;
                    if (q < 0 || q >= 14) continue;
                    int t = a * 3 + bq;
                    acc += cw[t] * x[p * 14 + q] + sB[t * 196 + p * 14 + q];
                }
            }
            y1s[i * 14 + j] = fmaxf(acc, 0.f) * scale + shift;
        }
    }
    __syncthreads();   // y1s + sWTf ready

    // Stage 2 (28x28)
    {
        int n = (r2hi - r2lo + 1) * 28;
        if (tid < n) {
            int i = r2lo + tid / 28, j = tid % 28;
            float acc = stage_pixel(i, j, 28, y1s, 14, sB + 1764, cw, bias);
            y2s[i * 28 + j] = fmaxf(acc, 0.f) * scale + shift;
        }
    }
    __syncthreads();

    // Stage 3 (56x56)
    {
        int n = (r3hi - r3lo + 1) * 56;
        if (tid < n) {
            int i = r3lo + tid / 56, j = tid % 56;
            float acc = stage_pixel(i, j, 56, y2s, 28, sB + 2 * 1764, cw, bias);
            y3s[i * 56 + j] = fmaxf(acc, 0.f) * scale + shift;
        }
    }
    __syncthreads();

    // Stage 4: rows y4lo..y4hi, slot rr = i-(b-1)
    {
        int n = (y4hi - y4lo + 1) * 112;
        if (tid < n) {
            int i = y4lo + tid / 112, j = tid % 112;
            float acc = stage_pixel(i, j, 112, y3s, 56, sB + 3 * 1764, cw, bias);
            y4loc[(i - (b - 1)) * 112 + j] = fmaxf(acc, 0.f) * scale + shift;
        }
    }
    __syncthreads();

    // D-row dots: D[i][o] = sum_k y4loc[i][k] * sWTf[k][o], K split in 4.
    // One sWTf (LDS) read feeds 3 FMAs. Garbage slots (unwritten y4loc at the
    // grid edge) produce garbage partials that the final phase never reads.
    if (tid < 896) {
        int kq = tid / 224, o = tid % 224;
        int k0 = kq * 28;
        float a0 = 0.f, a1 = 0.f, a2 = 0.f;
        for (int k = k0; k < k0 + 28; ++k) {
            float wf = sWTf[k * 224 + o];      // stride-1 over lanes: conflict-free
            a0 += y4loc[k] * wf;
            a1 += y4loc[112 + k] * wf;
            a2 += y4loc[224 + k] * wf;
        }
        partial[(0 * 4 + kq) * 224 + o] = a0;
        partial[(1 * 4 + kq) * 224 + o] = a1;
        partial[(2 * 4 + kq) * 224 + o] = a2;
    }
    __syncthreads();

    // up2-y lerp of D rows + bias + sigmoid
    if (tid < 448) {
        int rr = tid / 224, o = tid % 224;
        int r = 2 * b + rr;
        float hy = clampf(((float)r + 0.5f) * 0.5f - 0.5f, 0.f, 111.f);
        int yy0 = (int)hy; float fy = hy - (float)yy0; int yy1 = min(yy0 + 1, 111);
        int s0 = yy0 - (b - 1), s1 = yy1 - (b - 1);   // always in {1,2} at edges
        float D0 = partial[(s0 * 4 + 0) * 224 + o] + partial[(s0 * 4 + 1) * 224 + o]
                 + partial[(s0 * 4 + 2) * 224 + o] + partial[(s0 * 4 + 3) * 224 + o];
        float D1 = partial[(s1 * 4 + 0) * 224 + o] + partial[(s1 * 4 + 1) * 224 + o]
                 + partial[(s1 * 4 + 2) * 224 + o] + partial[(s1 * 4 + 3) * 224 + o];
        float v = (1.f - fy) * D0 + fy * D1 + W_b[o];
        out[(size_t)r * 224 + o] = 1.f / (1.f + expf(-v));
    }
}

extern "C" void kernel_launch(void* const* d_in, const int* in_sizes, int n_in,
                              void* d_out, int out_size, void* d_ws, size_t ws_size,
                              hipStream_t stream) {
    (void)in_sizes; (void)n_in; (void)out_size; (void)d_ws; (void)ws_size;
    const float* x      = (const float*)d_in[0];
    const float* fv     = (const float*)d_in[1];
    const float* conv_w = (const float*)d_in[2];
    const float* conv_b = (const float*)d_in[3];
    const float* bng    = (const float*)d_in[4];
    const float* bnb    = (const float*)d_in[5];
    const float* bnm    = (const float*)d_in[6];
    const float* bnv    = (const float*)d_in[7];
    const float* W_w    = (const float*)d_in[8];
    const float* W_b    = (const float*)d_in[9];
    float* out = (float*)d_out;

    refine_one<<<112, 1024, 0, stream>>>(x, fv, conv_w, conv_b, bng, bnb,
                                         bnm, bnv, W_w, W_b, out);
}

// Round 4
// 86.793 us; speedup vs baseline: 2.6296x; 2.6296x over previous
//
#include <hip/hip_runtime.h>
#include <math.h>

// ---------------------------------------------------------------------------
// Two-kernel Refiner (R0 structure restored) + LDS-staged WTf in kernel B.
//
// R9 post-mortems of R6-R8: every fusion variant regressed —
//   coop launch +32us (slow launch path), software grid barrier +55us
//   (device-scope fence/spin across 1792 waves), communication-free
//   redundancy +140us (112x uncoalesced W_w fold, 700MB L2 amplification).
// The kernel-A -> kernel-B dispatch boundary IS the cheap device-scope
// release. Keep it. Only change vs R0: kernel B copies gWTf into LDS
// (coalesced) during idle phase regions, so the D-dot loop reads LDS
// instead of L2.
//
// Algebra (carried): B[s][t][u][v] = sum_c conv_w[1+c][t]*f14[s][c][u][v];
// each stage's 768-ch feature term is one bilinear sample of B (BN affine
// commutes with lerp). Final up2-x folded into WTf[xx][o]; per-y4-row dots
// D[i][o] (K=112), then up2-y lerp of D rows + sigmoid.
// ---------------------------------------------------------------------------

#define BN_EPS 1e-5f

__device__ __forceinline__ float clampf(float x, float lo, float hi) {
    return fminf(fmaxf(x, lo), hi);
}

__device__ __forceinline__ float sampleB(const float* __restrict__ Bt, float fy, float fx) {
    int y0 = (int)fy; float by = fy - (float)y0; int y1 = min(y0 + 1, 13);
    int x0 = (int)fx; float bx = fx - (float)x0; int x1 = min(x0 + 1, 13);
    return (1.f - by) * ((1.f - bx) * Bt[y0 * 14 + x0] + bx * Bt[y0 * 14 + x1])
         + by         * ((1.f - bx) * Bt[y1 * 14 + x0] + bx * Bt[y1 * 14 + x1]);
}

// Conv accumulator (pre-ReLU/BN) for one pixel at resolution H (up-sampled h).
__device__ __forceinline__ float stage_pixel(int i, int j, int H,
                                             const float* __restrict__ hsrc, int srcH,
                                             const float* __restrict__ sB,
                                             const float* __restrict__ cw, float bias) {
    float featScale = 14.0f / (float)H;
    float srcMax = (float)(srcH - 1);
    float acc = bias;

#pragma unroll
    for (int a = 0; a < 3; ++a) {
        int p = i + a - 1;
        if (p < 0 || p >= H) continue;          // SAME zero padding
        float fy = clampf(((float)p + 0.5f) * featScale - 0.5f, 0.f, 13.f);
        float hy = clampf(((float)p + 0.5f) * 0.5f - 0.5f, 0.f, srcMax);
        int hy0 = (int)hy; float fhy = hy - (float)hy0; int hy1 = min(hy0 + 1, srcH - 1);
#pragma unroll
        for (int bq = 0; bq < 3; ++bq) {
            int q = j + bq - 1;
            if (q < 0 || q >= H) continue;
            int t = a * 3 + bq;

            float fx = clampf(((float)q + 0.5f) * featScale - 0.5f, 0.f, 13.f);
            float bv = sampleB(sB + t * 196, fy, fx);

            float hx = clampf(((float)q + 0.5f) * 0.5f - 0.5f, 0.f, srcMax);
            int hx0 = (int)hx; float fhx = hx - (float)hx0; int hx1 = min(hx0 + 1, srcH - 1);
            float hval = (1.f - fhy) * ((1.f - fhx) * hsrc[hy0 * srcH + hx0] + fhx * hsrc[hy0 * srcH + hx1])
                       + fhy         * ((1.f - fhx) * hsrc[hy1 * srcH + hx0] + fhx * hsrc[hy1 * srcH + hx1]);
            acc += cw[t] * hval + bv;
        }
    }
    return acc;
}

// src rows needed to compute dst rows [dlo,dhi] of a stage at H=2*srcH.
__device__ __forceinline__ void srcRange(int dlo, int dhi, int srcH, int& slo, int& shi) {
    int H = 2 * srcH;
    int p0 = max(dlo - 1, 0), p1 = min(dhi + 1, H - 1);
    float h0 = fmaxf(((float)p0 + 0.5f) * 0.5f - 0.5f, 0.f);
    float h1 = fmaxf(((float)p1 + 0.5f) * 0.5f - 0.5f, 0.f);
    slo = (int)h0;
    shi = min((int)h1 + 1, srcH - 1);
}

// B-plane rows of a stage's sB needed for dst rows [dlo,dhi] at resolution H.
__device__ __forceinline__ void bRange(int dlo, int dhi, int H, int& lo, int& hi) {
    float sc = 14.f / (float)H;
    int p0 = max(dlo - 1, 0), p1 = min(dhi + 1, H - 1);
    float f0 = clampf(((float)p0 + 0.5f) * sc - 0.5f, 0.f, 13.f);
    float f1 = clampf(((float)p1 + 0.5f) * sc - 0.5f, 0.f, 13.f);
    lo = (int)f0;
    hi = min((int)f1 + 1, 13);
}

// ---- Kernel A: B pre-reduction + folded (up2-x . W^T) weights ----
__global__ __launch_bounds__(256)
void compute_B_kernel(const float* __restrict__ fv, const float* __restrict__ conv_w,
                      const float* __restrict__ W_w,
                      float* __restrict__ gB, float* __restrict__ gWTf) {
    int blk = blockIdx.x;          // 0..783
    int s = blk / 196;
    int uv = blk % 196;
    const float* fvrow = fv + ((size_t)(3 - s) * 197 + 1 + uv) * 768;
    int tid = threadIdx.x;

    // folded weights: 784 blocks x 32 == 25088 == 112*224 exactly.
    // gWTf[xx*224+o] = sum_w coef(xx,w) * W[o][w], coef from the canonical
    // clamped half-pixel up2-x lerp (each xx gathers from w in [2xx-1,2xx+2]).
    if (tid < 32) {
        int idx = blk * 32 + tid;
        int o = idx % 224, xx = idx / 224;
        float acc = 0.f;
#pragma unroll
        for (int d = -1; d <= 2; ++d) {
            int w = 2 * xx + d;
            if (w < 0 || w > 223) continue;
            float hx = clampf(((float)w + 0.5f) * 0.5f - 0.5f, 0.f, 111.f);
            int xx0 = (int)hx; float fx = hx - (float)xx0; int xx1 = min(xx0 + 1, 111);
            float c = (xx0 == xx ? 1.f - fx : 0.f) + (xx1 == xx ? fx : 0.f);
            acc += c * W_w[o * 224 + w];
        }
        gWTf[xx * 224 + o] = acc;
    }

    float part[9];
#pragma unroll
    for (int t = 0; t < 9; ++t) part[t] = 0.f;
    for (int k = tid; k < 768; k += 256) {
        float fval = fvrow[k];
        const float* w = conv_w + (size_t)(1 + k) * 9;
#pragma unroll
        for (int t = 0; t < 9; ++t) part[t] += fval * w[t];
    }
#pragma unroll
    for (int t = 0; t < 9; ++t) {
#pragma unroll
        for (int off = 32; off > 0; off >>= 1)
            part[t] += __shfl_down(part[t], off, 64);
    }
    __shared__ float red[4][9];
    int wave = tid >> 6, lane = tid & 63;
    if (lane == 0) {
#pragma unroll
        for (int t = 0; t < 9; ++t) red[wave][t] = part[t];
    }
    __syncthreads();
    if (tid < 9)
        gB[s * 1764 + tid * 196 + uv] = red[0][tid] + red[1][tid] + red[2][tid] + red[3][tid];
}

// ---- Kernel B: cone-pruned stages + D-row dots + up2-y lerp + sigmoid ----
__global__ __launch_bounds__(1024, 1)
void refine_kernel(const float* __restrict__ x,
                   const float* __restrict__ conv_w, const float* __restrict__ conv_b,
                   const float* __restrict__ bng, const float* __restrict__ bnb,
                   const float* __restrict__ bnm, const float* __restrict__ bnv,
                   const float* __restrict__ W_b,
                   const float* __restrict__ gB, const float* __restrict__ gWTf,
                   float* __restrict__ out) {
    __shared__ float sB[4 * 9 * 196];      //  28224 B
    __shared__ float y1s[196];             //    784 B
    __shared__ float y2s[784];             //   3136 B
    __shared__ float y3s[3136];            //  12544 B
    __shared__ float y4loc[3 * 112];       //   1344 B
    __shared__ float partial[12 * 224];    //  10752 B
    __shared__ float sWTf[112 * 224];      // 100352 B  -> total 157136 B

    int tid = threadIdx.x;
    int b = blockIdx.x;

    // dependence cone of output rows 2b, 2b+1
    int y4lo = max(b - 1, 0), y4hi = min(b + 1, 111);
    int r3lo, r3hi; srcRange(y4lo, y4hi, 56, r3lo, r3hi);
    int r2lo, r2hi; srcRange(r3lo, r3hi, 28, r2lo, r2hi);
    int r1lo, r1hi; srcRange(r2lo, r2hi, 14, r1lo, r1hi);

    // B-plane row windows per stage
    int bl0 = max(r1lo - 1, 0), bh0 = min(r1hi + 1, 13);   // stage 1: integer coords
    int bl1, bh1; bRange(r2lo, r2hi, 28, bl1, bh1);
    int bl2, bh2; bRange(r3lo, r3hi, 56, bl2, bh2);
    int bl3, bh3; bRange(y4lo, y4hi, 112, bl3, bh3);

    // cone-only load of sB (contiguous row windows per (stage, tap) plane)
    {
        int bl[4] = {bl0, bl1, bl2, bl3}, bh[4] = {bh0, bh1, bh2, bh3};
#pragma unroll
        for (int s4 = 0; s4 < 4; ++s4) {
            int nrw = (bh[s4] - bl[s4] + 1) * 14;
            int n = 9 * nrw;
            int base = s4 * 1764 + bl[s4] * 14;
            for (int e = tid; e < n; e += 1024) {
                int t = e / nrw, rem = e % nrw;
                int off = base + t * 196 + rem;
                sB[off] = gB[off];
            }
        }
    }
    // sWTf copy, chunk 0 (all threads, coalesced): elems [0, 8192)
#pragma unroll
    for (int i = 0; i < 8; ++i)
        sWTf[tid + 1024 * i] = gWTf[tid + 1024 * i];

    float cw[9];
#pragma unroll
    for (int t = 0; t < 9; ++t) cw[t] = conv_w[t];
    float bias = conv_b[0];
    float scale = bng[0] * rsqrtf(bnv[0] + BN_EPS);
    float shift = bnb[0] - bnm[0] * scale;
    __syncthreads();

    // Stage 1 (14x14, h = x, B sampled at integer coords -> direct lookup)
    // Stage 1 uses <= ~98 threads; idle threads (>=128) copy sWTf chunk 1.
    {
        int n = (r1hi - r1lo + 1) * 14;
        if (tid < n) {
            int i = r1lo + tid / 14, j = tid % 14;
            float acc = bias;
#pragma unroll
            for (int a = 0; a < 3; ++a) {
                int p = i + a - 1;
                if (p < 0 || p >= 14) continue;
#pragma unroll
                for (int bq = 0; bq < 3; ++bq) {
                    int q = j + bq - 1;
                    if (q < 0 || q >= 14) continue;
                    int t = a * 3 + bq;
                    acc += cw[t] * x[p * 14 + q] + sB[t * 196 + p * 14 + q];
                }
            }
            y1s[i * 14 + j] = fmaxf(acc, 0.f) * scale + shift;
        }
    }
    if (tid >= 128) {
        // chunk 1: elems [8192, 17152)  (896 threads x 10)
#pragma unroll
        for (int i = 0; i < 10; ++i)
            sWTf[8192 + (tid - 128) + 896 * i] = gWTf[8192 + (tid - 128) + 896 * i];
    }
    __syncthreads();

    // Stage 2 (28x28); uses <= ~196 threads; idle threads (>=256) copy chunk 2.
    {
        int n = (r2hi - r2lo + 1) * 28;
        if (tid < n) {
            int i = r2lo + tid / 28, j = tid % 28;
            float acc = stage_pixel(i, j, 28, y1s, 14, sB + 1764, cw, bias);
            y2s[i * 28 + j] = fmaxf(acc, 0.f) * scale + shift;
        }
    }
    if (tid >= 256) {
        // chunk 2: elems [17152, 25088)  (768 threads x up-to-11, bound-checked)
#pragma unroll
        for (int i = 0; i < 11; ++i) {
            int e = 17152 + (tid - 256) + 768 * i;
            if (e < 25088) sWTf[e] = gWTf[e];
        }
    }
    __syncthreads();

    // Stage 3 (56x56)
    {
        int n = (r3hi - r3lo + 1) * 56;
        if (tid < n) {
            int i = r3lo + tid / 56, j = tid % 56;
            float acc = stage_pixel(i, j, 56, y2s, 28, sB + 2 * 1764, cw, bias);
            y3s[i * 56 + j] = fmaxf(acc, 0.f) * scale + shift;
        }
    }
    __syncthreads();

    // Stage 4: rows y4lo..y4hi, slot rr = i-(b-1)
    {
        int n = (y4hi - y4lo + 1) * 112;
        if (tid < n) {
            int i = y4lo + tid / 112, j = tid % 112;
            float acc = stage_pixel(i, j, 112, y3s, 56, sB + 3 * 1764, cw, bias);
            y4loc[(i - (b - 1)) * 112 + j] = fmaxf(acc, 0.f) * scale + shift;
        }
    }
    __syncthreads();

    // D-row dots: D[i][o] = sum_k y4loc[i][k] * sWTf[k][o], K split in 4.
    // One LDS read feeds 3 FMAs; lanes hit consecutive banks (2/bank = free).
    // Garbage slots (unwritten y4loc at the grid edge) produce garbage
    // partials that the final phase never reads.
    if (tid < 896) {
        int kq = tid / 224, o = tid % 224;
        int k0 = kq * 28;
        float a0 = 0.f, a1 = 0.f, a2 = 0.f;
        for (int k = k0; k < k0 + 28; ++k) {
            float wf = sWTf[k * 224 + o];
            a0 += y4loc[k] * wf;
            a1 += y4loc[112 + k] * wf;
            a2 += y4loc[224 + k] * wf;
        }
        partial[(0 * 4 + kq) * 224 + o] = a0;
        partial[(1 * 4 + kq) * 224 + o] = a1;
        partial[(2 * 4 + kq) * 224 + o] = a2;
    }
    __syncthreads();

    // up2-y lerp of D rows + bias + sigmoid
    if (tid < 448) {
        int rr = tid / 224, o = tid % 224;
        int r = 2 * b + rr;
        float hy = clampf(((float)r + 0.5f) * 0.5f - 0.5f, 0.f, 111.f);
        int yy0 = (int)hy; float fy = hy - (float)yy0; int yy1 = min(yy0 + 1, 111);
        int s0 = yy0 - (b - 1), s1 = yy1 - (b - 1);   // always in {1,2} at edges
        float D0 = partial[(s0 * 4 + 0) * 224 + o] + partial[(s0 * 4 + 1) * 224 + o]
                 + partial[(s0 * 4 + 2) * 224 + o] + partial[(s0 * 4 + 3) * 224 + o];
        float D1 = partial[(s1 * 4 + 0) * 224 + o] + partial[(s1 * 4 + 1) * 224 + o]
                 + partial[(s1 * 4 + 2) * 224 + o] + partial[(s1 * 4 + 3) * 224 + o];
        float v = (1.f - fy) * D0 + fy * D1 + W_b[o];
        out[(size_t)r * 224 + o] = 1.f / (1.f + expf(-v));
    }
}

extern "C" void kernel_launch(void* const* d_in, const int* in_sizes, int n_in,
                              void* d_out, int out_size, void* d_ws, size_t ws_size,
                              hipStream_t stream) {
    (void)in_sizes; (void)n_in; (void)out_size; (void)ws_size;
    const float* x      = (const float*)d_in[0];
    const float* fv     = (const float*)d_in[1];
    const float* conv_w = (const float*)d_in[2];
    const float* conv_b = (const float*)d_in[3];
    const float* bng    = (const float*)d_in[4];
    const float* bnb    = (const float*)d_in[5];
    const float* bnm    = (const float*)d_in[6];
    const float* bnv    = (const float*)d_in[7];
    const float* W_w    = (const float*)d_in[8];
    const float* W_b    = (const float*)d_in[9];
    float* out = (float*)d_out;

    float* ws   = (float*)d_ws;
    float* gB   = ws;             // 7056 floats
    float* gWTf = ws + 7056;      // 25088 floats (112 x 224)

    compute_B_kernel<<<784, 256, 0, stream>>>(fv, conv_w, W_w, gB, gWTf);
    refine_kernel<<<112, 1024, 0, stream>>>(x, conv_w, conv_b, bng, bnb, bnm, bnv,
                                            W_b, gB, gWTf, out);
}